// Round 10
// baseline (368.812 us; speedup 1.0000x reference)
//
#include <hip/hip_runtime.h>

// LTAE2d fused pipeline, MI355X (gfx950). f32 I/O, fp16 MFMA internals, f32 accum.
// Round 10 = round 7 (PASS, 364us) + ONE axis: ph8b/8c multi-accumulator ILP
// with SCALAR LDS loads of OS/QB. Probe: R9 (same ILP, f32x4 LDS loads) failed
// 0.449; all passing rounds use scalar OS/QB loads. Everything else is R7 verbatim.

typedef __attribute__((ext_vector_type(8))) _Float16 f16x8;
typedef __attribute__((ext_vector_type(4))) _Float16 f16x4;
typedef __attribute__((ext_vector_type(4))) float f32x4;
typedef __attribute__((ext_vector_type(2))) float f32x2;

#define EPSF 1e-5f

__device__ __forceinline__ int swz(int r) { return (r & 7) << 4; }

// ---------------- k_pre (grid=8) ---------------- (unchanged)
__global__ __launch_bounds__(256) void k_pre(
    const float* __restrict__ Wc, const float* __restrict__ g1,
    const float* __restrict__ b1, const float* __restrict__ bc,
    const float* __restrict__ Wk, const float* __restrict__ Wq,
    const float* __restrict__ W2,
    float* __restrict__ u, float* __restrict__ v,
    _Float16* __restrict__ WcP, _Float16* __restrict__ WkP,
    float* __restrict__ WqT4, float* __restrict__ W2T4) {
    const int tid = threadIdx.x, bid = blockIdx.x;

    if (bid == 0) {  // u, v
        int j = tid;
        float su = 0.f, sv = 0.f;
        for (int c = 0; c < 128; c += 4) {
            f32x4 w = *(const f32x4*)(Wc + j * 128 + c);
            f32x4 g = *(const f32x4*)(g1 + c);
            f32x4 b = *(const f32x4*)(b1 + c);
#pragma unroll
            for (int e = 0; e < 4; ++e) { su += g[e] * w[e]; sv += b[e] * w[e]; }
        }
        u[j] = su;
        v[j] = sv + bc[j];
    }

    // WcP: 4096 f16x8 chunks, chunk ch = ((w*16 + ct*4 + ks)*64 + lane)
#pragma unroll
    for (int i = 0; i < 2; ++i) {
        int ch = bid * 512 + i * 256 + tid;
        int lane = ch & 63, ks = (ch >> 6) & 3, ct = (ch >> 8) & 3, w = ch >> 10;
        int j = w * 64 + ct * 16 + (lane & 15);
        int k0 = ks * 32 + (lane >> 4) * 8;
        f16x8 f;
#pragma unroll
        for (int h = 0; h < 2; ++h) {
            f32x4 wv = *(const f32x4*)(Wc + j * 128 + k0 + h * 4);
            f32x4 gv = *(const f32x4*)(g1 + k0 + h * 4);
#pragma unroll
            for (int e = 0; e < 4; ++e) f[h * 4 + e] = (_Float16)(wv[e] * gv[e]);
        }
        *(f16x8*)(WcP + ch * 8) = f;
    }

    // WkP: 2048 chunks, ch = ((w*8 + ks)*64 + lane)
    {
        int ch = bid * 256 + tid;
        int lane = ch & 63, ks = (ch >> 6) & 7, w = ch >> 9;
        int a = w * 16 + (lane & 15);
        int k0 = ks * 32 + (lane >> 4) * 8;
        f16x8 f;
#pragma unroll
        for (int h = 0; h < 2; ++h) {
            f32x4 wv = *(const f32x4*)(Wk + a * 256 + k0 + h * 4);
#pragma unroll
            for (int e = 0; e < 4; ++e) f[h * 4 + e] = (_Float16)wv[e];
        }
        *(f16x8*)(WkP + ch * 8) = f;
    }

    // WqT4: 4096 f32x4 chunks, idx = kb*64 + a; value = Wq[a][kb*4+e]
#pragma unroll
    for (int i = 0; i < 2; ++i) {
        int idx = bid * 512 + i * 256 + tid;
        int a = idx & 63, kb = idx >> 6;
        f32x4 wv = *(const f32x4*)(Wq + a * 256 + kb * 4);
        *(f32x4*)(WqT4 + idx * 4) = wv;
    }

    // W2T4: 1024 chunks, idx = kb*64 + a2; value = W2[a2][kb*4+e]
    if (tid < 128) {
        int idx = bid * 128 + tid;
        int a2 = idx & 63, kb = idx >> 6;
        f32x4 wv = *(const f32x4*)(W2 + a2 * 64 + kb * 4);
        *(f32x4*)(W2T4 + idx * 4) = wv;
    }
}

// ---------------- k_main ----------------
// LDS layout (bytes), 2px/block, phase-aliased (hazards barrier-separated):
#define XS_OFF 0        // [48][128] f16 swz (12288); ph7+: KS f32[48][64] (12288)
#define OUTS_OFF 12288  // [48][256] f16 swz (24576)
#define AST_OFF 36864   // f32[48]
#define BST_OFF 37056   // f32[48]
#define U_OFF 37248     // f32[256]; OS f32[2][256] aliases U+V after ph4
#define V_OFF 38272     // f32[256]
#define G2_OFF 39296    // f32[256]; QB f32[2][64] @39296, Q2 @39808 after ph6
#define B2_OFF 40320    // f16[256]
#define SM1_SIZE 40832

#define KS_OFF 0
#define OS_OFF 37248
#define QB_OFF 39296
#define Q2_OFF 39808
#define ATTT_OFF 37248  // f32[48][16] = 3072 B over OS+QB+Q2 (after 9a barrier)

__global__ __launch_bounds__(256, 4) void k_main(
    const float* __restrict__ x,
    const float* __restrict__ uarr, const float* __restrict__ varr,
    const _Float16* __restrict__ WcP, const _Float16* __restrict__ WkP,
    const float* __restrict__ WqT4, const float* __restrict__ W2T4,
    const float* __restrict__ g2, const float* __restrict__ b2ln,
    const float* __restrict__ bq,
    const float* __restrict__ rm1, const float* __restrict__ rv1,
    const float* __restrict__ bg1, const float* __restrict__ bb1,
    const float* __restrict__ b2fc, const float* __restrict__ bk,
    _Float16* __restrict__ o_ws) {
    extern __shared__ char sm[];
    const int tid = threadIdx.x;
    const int lane = tid & 63;
    const int wave = tid >> 6;
    const int lrow = lane & 15;
    const int lkg = lane >> 4;  // 0..3
    // XCD-chunked swizzle: grid=8192, 8 XCDs, 1024 ids/chunk (bijective).
    const int wid = ((blockIdx.x & 7) << 10) | (blockIdx.x >> 3);
    const int p0 = wid * 2;
    const int bb = p0 >> 12;
    const int hh = (p0 >> 6) & 63;
    const int w0 = p0 & 63;  // even

    char* XS = sm + XS_OFF;
    char* OUTS = sm + OUTS_OFF;
    float* AST = (float*)(sm + AST_OFF);
    float* BST = (float*)(sm + BST_OFF);
    float* UU = (float*)(sm + U_OFF);
    float* VV = (float*)(sm + V_OFF);
    float* G2F = (float*)(sm + G2_OFF);
    _Float16* B2H = (_Float16*)(sm + B2_OFF);
    float* OS = (float*)(sm + OS_OFF);
    float* QB = (float*)(sm + QB_OFF);
    float* Q2 = (float*)(sm + Q2_OFF);
    float* ATTT = (float*)(sm + ATTT_OFF);
    float* KS = (float*)(sm + KS_OFF);

    // phase 0: LUTs
    UU[tid] = uarr[tid];
    VV[tid] = varr[tid];
    G2F[tid] = g2[tid];
    B2H[tid] = (_Float16)b2ln[tid];

    // phase 1: x tile -> XS (f32 -> f16, swizzled). rows r = pix*24+t, cols c.
#pragma unroll
    for (int i = 0; i < 12; ++i) {
        int idx = tid + i * 256;  // [0,3072)
        int c = idx / 24;
        int t = idx - c * 24;
        size_t go = (((size_t)((bb * 128 + c) * 24 + t)) << 12) + hh * 64 + w0;
        f32x2 xv = *(const f32x2*)(x + go);
#pragma unroll
        for (int p = 0; p < 2; ++p) {
            int r = p * 24 + t;
            *(_Float16*)(XS + r * 256 + ((c * 2) ^ swz(r))) = (_Float16)xv[p];
        }
    }
    __syncthreads();

    // phase 2: per-row mean/var of x (LN1 stats) — serial form (round 7)
    if (tid < 48) {
        int r = tid;
        float s = 0.f, sq = 0.f;
        for (int kb = 0; kb < 16; ++kb) {
            f16x8 v8 = *(const f16x8*)(XS + r * 256 + ((kb * 16) ^ swz(r)));
#pragma unroll
            for (int e = 0; e < 8; ++e) { float f = (float)v8[e]; s += f; sq += f * f; }
        }
        float m = s * (1.f / 128.f);
        float var = sq * (1.f / 128.f) - m * m;
        float inv = rsqrtf(var + EPSF);
        AST[r] = inv;
        BST[r] = m * inv;
    }

    // phase 3: B-fragments from WcP (coalesced, frag-ordered, g1-scaled)
    const int colbase = wave * 64;
    const _Float16* wcp = WcP + (size_t)wave * 1024 * 8;
    f16x8 bfr[4][4];
#pragma unroll
    for (int ct = 0; ct < 4; ++ct)
#pragma unroll
        for (int ks = 0; ks < 4; ++ks)
            bfr[ct][ks] = *(const f16x8*)(wcp + ((ct * 4 + ks) * 64 + lane) * 8);
    __syncthreads();

    // phase 4: GEMM-A (out_pre = S*inv1 - (m1*inv1)*u + v), store f16 -> OUTS
#pragma unroll 1
    for (int rt = 0; rt < 3; ++rt) {
        int ra = rt * 16 + lrow;
        f16x8 af[4];
#pragma unroll
        for (int ks = 0; ks < 4; ++ks)
            af[ks] = *(const f16x8*)(XS + ra * 256 + ((ks * 64 + lkg * 16) ^ swz(ra)));
        f32x4 acc[4] = {};
#pragma unroll
        for (int ct = 0; ct < 4; ++ct)
#pragma unroll
            for (int ks = 0; ks < 4; ++ks)
                acc[ct] = __builtin_amdgcn_mfma_f32_16x16x32_f16(af[ks], bfr[ct][ks], acc[ct], 0, 0, 0);
        float a1r[4], b1r[4];
#pragma unroll
        for (int reg = 0; reg < 4; ++reg) {
            int rr = rt * 16 + lkg * 4 + reg;
            a1r[reg] = AST[rr];
            b1r[reg] = BST[rr];
        }
#pragma unroll
        for (int ct = 0; ct < 4; ++ct) {
            int j = colbase + ct * 16 + lrow;
            float uj = UU[j], vj = VV[j];
#pragma unroll
            for (int reg = 0; reg < 4; ++reg) {
                int rr = rt * 16 + lkg * 4 + reg;
                float val = acc[ct][reg] * a1r[reg] - b1r[reg] * uj + vj;
                *(_Float16*)(OUTS + rr * 512 + ((j * 2) ^ swz(rr))) = (_Float16)val;
            }
        }
    }
    __syncthreads();

    // phase 5: LN2 stats — serial form (round 7)
    if (tid < 48) {
        int r = tid;
        float s = 0.f, sq = 0.f;
        for (int kb = 0; kb < 32; ++kb) {
            f16x8 v8 = *(const f16x8*)(OUTS + r * 512 + ((kb * 16) ^ swz(r)));
#pragma unroll
            for (int e = 0; e < 8; ++e) { float f = (float)v8[e]; s += f; sq += f * f; }
        }
        float m = s * (1.f / 256.f);
        float var = sq * (1.f / 256.f) - m * m;
        float inv = rsqrtf(var + EPSF);
        AST[r] = inv;
        BST[r] = m * inv;
    }
    __syncthreads();

    // phase 6: LN2 normalize in place (+g2,+b2) — round-7 form (2 thr/row)
    if (tid < 96) {
        int r = tid >> 1;
        int half = tid & 1;
        float a2r = AST[r], b2r = BST[r];
#pragma unroll
        for (int q = 0; q < 16; ++q) {
            int kb = half * 16 + q;
            char* p = OUTS + r * 512 + ((kb * 16) ^ swz(r));
            f16x8 v8 = *(const f16x8*)p;
#pragma unroll
            for (int e = 0; e < 8; ++e) {
                int j = kb * 8 + e;
                float f = (float)v8[e];
                f = f * a2r - b2r;
                f = f * G2F[j] + (float)B2H[j];
                v8[e] = (_Float16)f;
            }
            *(f16x8*)p = v8;
        }
    }
    __syncthreads();

    // phase 7: k-projection GEMM -> KS f32 [48][64] (over dead XS region)
    {
        int aa = wave * 16 + lrow;
        const _Float16* wkp = WkP + (size_t)wave * 512 * 8;
        f16x8 kbf[8];
#pragma unroll
        for (int ks = 0; ks < 8; ++ks)
            kbf[ks] = *(const f16x8*)(wkp + (ks * 64 + lane) * 8);
        float bkf = bk[aa];
#pragma unroll 1
        for (int rt = 0; rt < 3; ++rt) {
            int ra = rt * 16 + lrow;
            f32x4 acc = {};
#pragma unroll
            for (int ks = 0; ks < 8; ++ks) {
                f16x8 af = *(const f16x8*)(OUTS + ra * 512 + ((ks * 64 + lkg * 16) ^ swz(ra)));
                acc = __builtin_amdgcn_mfma_f32_16x16x32_f16(af, kbf[ks], acc, 0, 0, 0);
            }
#pragma unroll
            for (int reg = 0; reg < 4; ++reg) {
                int rr = rt * 16 + lkg * 4 + reg;
                KS[rr * 64 + aa] = acc[reg] + bkf;
            }
        }
    }
    __syncthreads();

    // phase 8a: outsum (mean over T) -> OS — round-7 form (1 thr per 8 cols)
    if (tid < 64) {
        int pix = tid >> 5, j8 = tid & 31;
        float s[8] = {};
#pragma unroll
        for (int t = 0; t < 24; ++t) {
            int r = pix * 24 + t;
            f16x8 v8 = *(const f16x8*)(OUTS + r * 512 + ((j8 * 16) ^ swz(r)));
#pragma unroll
            for (int e = 0; e < 8; ++e) s[e] += (float)v8[e];
        }
#pragma unroll
        for (int e = 0; e < 8; ++e) OS[pix * 256 + j8 * 8 + e] = s[e] * (1.f / 24.f);
    }
    __syncthreads();

    // phase 8b: q_pre = os @ Wq.T + bq; then bn1 — ILP (4 accumulators),
    // SCALAR OS loads (probe: R9's f32x4 OS loads failed; scalar passes in R7)
    if (tid < 128) {
        int pix = tid >> 6;
        int a = tid & 63;
        const float* osp = OS + pix * 256;
        float qa0 = 0.f, qa1 = 0.f, qa2 = 0.f, qa3 = 0.f;
#pragma unroll 2
        for (int kb = 0; kb < 64; kb += 4) {
            f32x4 w0 = *(const f32x4*)(WqT4 + ((kb + 0) * 64 + a) * 4);
            f32x4 w1 = *(const f32x4*)(WqT4 + ((kb + 1) * 64 + a) * 4);
            f32x4 w2 = *(const f32x4*)(WqT4 + ((kb + 2) * 64 + a) * 4);
            f32x4 w3 = *(const f32x4*)(WqT4 + ((kb + 3) * 64 + a) * 4);
            qa0 += osp[kb * 4 + 0] * w0[0] + osp[kb * 4 + 1] * w0[1] +
                   osp[kb * 4 + 2] * w0[2] + osp[kb * 4 + 3] * w0[3];
            qa1 += osp[kb * 4 + 4] * w1[0] + osp[kb * 4 + 5] * w1[1] +
                   osp[kb * 4 + 6] * w1[2] + osp[kb * 4 + 7] * w1[3];
            qa2 += osp[kb * 4 + 8] * w2[0] + osp[kb * 4 + 9] * w2[1] +
                   osp[kb * 4 + 10] * w2[2] + osp[kb * 4 + 11] * w2[3];
            qa3 += osp[kb * 4 + 12] * w3[0] + osp[kb * 4 + 13] * w3[1] +
                   osp[kb * 4 + 14] * w3[2] + osp[kb * 4 + 15] * w3[3];
        }
        float qp = ((qa0 + qa1) + (qa2 + qa3)) + bq[a];
        float sc = rsqrtf(rv1[a] + EPSF);
        QB[pix * 64 + a] = (qp - rm1[a]) * sc * bg1[a] + bb1[a];
    }
    __syncthreads();

    // phase 8c: q2 = qbn @ W2.T + b2 — ILP (2 accumulators), SCALAR QB loads
    if (tid < 128) {
        int pix = tid >> 6;
        int a2 = tid & 63;
        const float* qbp = QB + pix * 64;
        float s0 = 0.f, s1 = 0.f;
#pragma unroll
        for (int kb = 0; kb < 16; kb += 2) {
            f32x4 w0 = *(const f32x4*)(W2T4 + ((kb + 0) * 64 + a2) * 4);
            f32x4 w1 = *(const f32x4*)(W2T4 + ((kb + 1) * 64 + a2) * 4);
            s0 += qbp[kb * 4 + 0] * w0[0] + qbp[kb * 4 + 1] * w0[1] +
                  qbp[kb * 4 + 2] * w0[2] + qbp[kb * 4 + 3] * w0[3];
            s1 += qbp[kb * 4 + 4] * w1[0] + qbp[kb * 4 + 5] * w1[1] +
                  qbp[kb * 4 + 6] * w1[2] + qbp[kb * 4 + 7] * w1[3];
        }
        Q2[pix * 64 + a2] = (s0 + s1) + b2fc[a2];
    }
    __syncthreads();

    // phase 9a: scores + softmax (f32 KS) -> regs
    float att[24];
    if (tid < 32) {
        int pix = tid >> 4, hd = tid & 15;
        float q0 = Q2[pix * 64 + hd * 4 + 0];
        float q1 = Q2[pix * 64 + hd * 4 + 1];
        float q2v = Q2[pix * 64 + hd * 4 + 2];
        float q3 = Q2[pix * 64 + hd * 4 + 3];
        float mx = -1e30f;
#pragma unroll
        for (int t = 0; t < 24; ++t) {
            const float* kp = KS + (pix * 24 + t) * 64 + hd * 4;
            float s = 0.5f * (q0 * kp[0] + q1 * kp[1] + q2v * kp[2] + q3 * kp[3]);
            att[t] = s;
            mx = fmaxf(mx, s);
        }
        float sum = 0.f;
#pragma unroll
        for (int t = 0; t < 24; ++t) { float e = __expf(att[t] - mx); att[t] = e; sum += e; }
        float is = 1.f / sum;
#pragma unroll
        for (int t = 0; t < 24; ++t) att[t] *= is;
    }
    __syncthreads();  // Q2/KS reads done before ATTT overwrites

    // phase 9b: write attn weights TRANSPOSED -> ATTT [r][16h]
    if (tid < 32) {
        int pix = tid >> 4, hd = tid & 15;
#pragma unroll
        for (int t = 0; t < 24; ++t) ATTT[(pix * 24 + t) * 16 + hd] = att[t];
    }
    __syncthreads();

    // phase 10: o[n, h*256+d] = sum_t attn[h,t]*out[t,d]
    // 2 waves/pixel, 8 heads each; vector (broadcast) ATT loads.
    {
        int pix = wave >> 1;
        int hgrp = (wave & 1) * 8;
        f32x4 oa[8] = {};
#pragma unroll 1
        for (int t = 0; t < 24; ++t) {
            int r = pix * 24 + t;
            f16x4 v4 = *(const f16x4*)(OUTS + r * 512 + ((lane * 8) ^ swz(r)));
            f32x4 vf = {(float)v4[0], (float)v4[1], (float)v4[2], (float)v4[3]};
            f32x4 a0 = *(const f32x4*)(ATTT + r * 16 + hgrp);
            f32x4 a1 = *(const f32x4*)(ATTT + r * 16 + hgrp + 4);
#pragma unroll
            for (int h = 0; h < 4; ++h) oa[h] += a0[h] * vf;
#pragma unroll
            for (int h = 0; h < 4; ++h) oa[4 + h] += a1[h] * vf;
        }
        _Float16* op = o_ws + (size_t)(p0 + pix) * 4096 + (size_t)hgrp * 256 + lane * 4;
#pragma unroll
        for (int h = 0; h < 8; ++h) {
            f16x4 pk = {(_Float16)oa[h][0], (_Float16)oa[h][1],
                        (_Float16)oa[h][2], (_Float16)oa[h][3]};
            *(f16x4*)(op + h * 256) = pk;
        }
    }
}

// ---------------- k_mlp ---------------- (unchanged)
#define OT_OFF 0       // [64][256] f16 swz (32768); ZB aliases after GEMM
#define WT_OFF 32768   // [128][256] f16 swz (65536)
#define SC2_OFF 98304  // f32[128]
#define SH2_OFF 98816
#define G3_OFF 99328
#define B3_OFF 99840
#define A3_OFF 100352  // f32[64]
#define B3R_OFF 100608
#define SM3_SIZE 100864

__global__ __launch_bounds__(256) void k_mlp(
    const _Float16* __restrict__ o_ws,
    const float* __restrict__ Wm, const float* __restrict__ bm,
    const float* __restrict__ rm2, const float* __restrict__ rv2,
    const float* __restrict__ bg2, const float* __restrict__ bb2,
    const float* __restrict__ g3, const float* __restrict__ b3,
    float* __restrict__ out) {
    extern __shared__ char sm[];
    const int tid = threadIdx.x;
    const int lane = tid & 63;
    const int wave = tid >> 6;
    const int lrow = lane & 15;
    const int lkg = lane >> 4;
    const int n0 = blockIdx.x * 64;
    const int bb = blockIdx.x >> 6;
    const int hh = blockIdx.x & 63;

    char* OT = sm + OT_OFF;
    char* WT = sm + WT_OFF;
    char* ZB = sm + OT_OFF;  // f32 [64][128] swz, alias
    float* SC2 = (float*)(sm + SC2_OFF);
    float* SH2 = (float*)(sm + SH2_OFF);
    float* G3F = (float*)(sm + G3_OFF);
    float* B3F = (float*)(sm + B3_OFF);
    float* A3 = (float*)(sm + A3_OFF);
    float* B3R = (float*)(sm + B3R_OFF);

    if (tid < 128) {
        float sc = bg2[tid] * rsqrtf(rv2[tid] + EPSF);
        SC2[tid] = sc;
        SH2[tid] = bb2[tid] - rm2[tid] * sc + bm[tid] * sc;
        G3F[tid] = g3[tid];
        B3F[tid] = b3[tid];
    }

    const int colbase = wave * 32;
    f32x4 acc[4][2] = {};

    for (int kc = 0; kc < 16; ++kc) {
        __syncthreads();
#pragma unroll
        for (int i = 0; i < 8; ++i) {
            int fl = tid + i * 256;
            int r = fl >> 5, kk = fl & 31;
            f16x8 v = *(const f16x8*)(o_ws + (size_t)(n0 + r) * 4096 + kc * 256 + kk * 8);
            *(f16x8*)(OT + r * 512 + ((kk * 16) ^ swz(r))) = v;
        }
#pragma unroll
        for (int i = 0; i < 16; ++i) {
            int fl = tid + i * 256;
            int m = fl >> 5, kk = fl & 31;
            f16x8 f;
#pragma unroll
            for (int h = 0; h < 2; ++h) {
                f32x4 w = *(const f32x4*)(Wm + (size_t)m * 4096 + kc * 256 + kk * 8 + h * 4);
#pragma unroll
                for (int e = 0; e < 4; ++e) f[h * 4 + e] = (_Float16)w[e];
            }
            *(f16x8*)(WT + m * 512 + ((kk * 16) ^ swz(m))) = f;
        }
        __syncthreads();
        f16x8 bfr[2][8];
#pragma unroll
        for (int ct = 0; ct < 2; ++ct) {
            int m = colbase + ct * 16 + lrow;
#pragma unroll
            for (int ks = 0; ks < 8; ++ks)
                bfr[ct][ks] = *(const f16x8*)(WT + m * 512 + ((ks * 64 + lkg * 16) ^ swz(m)));
        }
#pragma unroll
        for (int rt = 0; rt < 4; ++rt) {
            int ra = rt * 16 + lrow;
#pragma unroll
            for (int ks = 0; ks < 8; ++ks) {
                f16x8 af = *(const f16x8*)(OT + ra * 512 + ((ks * 64 + lkg * 16) ^ swz(ra)));
#pragma unroll
                for (int ct = 0; ct < 2; ++ct)
                    acc[rt][ct] = __builtin_amdgcn_mfma_f32_16x16x32_f16(af, bfr[ct][ks], acc[rt][ct], 0, 0, 0);
            }
        }
    }
    __syncthreads();
#pragma unroll
    for (int rt = 0; rt < 4; ++rt) {
#pragma unroll
        for (int ct = 0; ct < 2; ++ct) {
            int m = colbase + ct * 16 + lrow;
            float sc = SC2[m], sh = SH2[m];
#pragma unroll
            for (int reg = 0; reg < 4; ++reg) {
                int rr = rt * 16 + lkg * 4 + reg;
                float z = acc[rt][ct][reg] * sc + sh;
                z = fmaxf(z, 0.f);
                *(float*)(ZB + rr * 512 + ((m * 4) ^ swz(rr))) = z;
            }
        }
    }
    __syncthreads();
    if (tid < 64) {
        int r = tid;
        float s = 0.f, sq = 0.f;
#pragma unroll
        for (int mb = 0; mb < 32; ++mb) {
            f32x4 v = *(const f32x4*)(ZB + r * 512 + ((mb * 16) ^ swz(r)));
#pragma unroll
            for (int e = 0; e < 4; ++e) { s += v[e]; sq += v[e] * v[e]; }
        }
        float m = s * (1.f / 128.f);
        float var = sq * (1.f / 128.f) - m * m;
        float inv = rsqrtf(var + EPSF);
        A3[r] = inv;
        B3R[r] = m * inv;
    }
    __syncthreads();
    {
        int m = tid >> 1;
        int half = tid & 1;
        float g = G3F[m], b = B3F[m];
        float vals[32];
#pragma unroll
        for (int i = 0; i < 32; ++i) {
            int w = half * 32 + i;
            float z = *(const float*)(ZB + w * 512 + ((m * 4) ^ swz(w)));
            vals[i] = (z * A3[w] - B3R[w]) * g + b;
        }
        float* po = out + ((size_t)(bb * 128 + m) * 64 + hh) * 64 + half * 32;
#pragma unroll
        for (int j = 0; j < 8; ++j) {
            f32x4 pk = {vals[j * 4], vals[j * 4 + 1], vals[j * 4 + 2], vals[j * 4 + 3]};
            *(f32x4*)(po + j * 4) = pk;
        }
    }
}

extern "C" void kernel_launch(void* const* d_in, const int* in_sizes, int n_in,
                              void* d_out, int out_size, void* d_ws, size_t ws_size,
                              hipStream_t stream) {
    const float* x = (const float*)d_in[0];
    const float* g1 = (const float*)d_in[1];
    const float* b1 = (const float*)d_in[2];
    const float* Wc = (const float*)d_in[3];
    const float* bc = (const float*)d_in[4];
    const float* g2 = (const float*)d_in[5];
    const float* b2l = (const float*)d_in[6];
    const float* Wq = (const float*)d_in[7];
    const float* bq = (const float*)d_in[8];
    const float* rm1 = (const float*)d_in[9];
    const float* rv1 = (const float*)d_in[10];
    const float* bg1 = (const float*)d_in[11];
    const float* bb1 = (const float*)d_in[12];
    const float* W2 = (const float*)d_in[13];
    const float* b2f = (const float*)d_in[14];
    const float* Wk = (const float*)d_in[15];
    const float* bk = (const float*)d_in[16];
    const float* Wm = (const float*)d_in[17];
    const float* bm = (const float*)d_in[18];
    const float* rm2 = (const float*)d_in[19];
    const float* rv2 = (const float*)d_in[20];
    const float* bg2 = (const float*)d_in[21];
    const float* bb2 = (const float*)d_in[22];
    const float* g3 = (const float*)d_in[23];
    const float* b3 = (const float*)d_in[24];

    // ws layout (byte offsets):
    //   0       u      f32[256]
    //   1024    v      f32[256]
    //   2048    WcP    f16[32768]   (64 KB)
    //   67584   WkP    f16[16384]   (32 KB)
    //   100352  WqT4   f32[16384]   (64 KB)
    //   165888  W2T4   f32[4096]    (16 KB)
    //   182272  o_ws   f16[16384*4096] (128 MiB)
    float* u = (float*)d_ws;
    float* v = u + 256;
    _Float16* WcP = (_Float16*)((char*)d_ws + 2048);
    _Float16* WkP = (_Float16*)((char*)d_ws + 67584);
    float* WqT4 = (float*)((char*)d_ws + 100352);
    float* W2T4 = (float*)((char*)d_ws + 165888);
    _Float16* o_ws = (_Float16*)((char*)d_ws + 182272);

    (void)hipFuncSetAttribute((const void*)k_mlp,
                              hipFuncAttributeMaxDynamicSharedMemorySize, SM3_SIZE);

    k_pre<<<8, 256, 0, stream>>>(Wc, g1, b1, bc, Wk, Wq, W2, u, v, WcP, WkP, WqT4, W2T4);
    k_main<<<8192, 256, SM1_SIZE, stream>>>(x, u, v, WcP, WkP, WqT4, W2T4,
                                            g2, b2l, bq, rm1, rv1, bg1, bb1, b2f, bk, o_ws);
    k_mlp<<<256, 256, SM3_SIZE, stream>>>(o_ws, Wm, bm, rm2, rv2, bg2, bb2, g3, b3,
                                          (float*)d_out);
}

// Round 11
// 355.806 us; speedup vs baseline: 1.0366x; 1.0366x over previous
//
#include <hip/hip_runtime.h>

// LTAE2d fused pipeline, MI355X (gfx950). f32 I/O, fp16 MFMA internals, f32 accum.
// Round 11 = round 10 (PASS, 369us) + ONE axis: ph2/ph5 LN-stats parallelized
// via LDS scratch partials (R8's form, now exonerated: all prior failures are
// fully explained by f32x4 LDS reads of OS/QB, which R10 removed).
// HAZARD RULE (empirical, rounds 4/5/8/9 vs 3/6/7/10): never read the OS/QB
// LDS regions through explicit f32x4 casts; scalar float reads only.

typedef __attribute__((ext_vector_type(8))) _Float16 f16x8;
typedef __attribute__((ext_vector_type(4))) _Float16 f16x4;
typedef __attribute__((ext_vector_type(4))) float f32x4;
typedef __attribute__((ext_vector_type(2))) float f32x2;

#define EPSF 1e-5f

__device__ __forceinline__ int swz(int r) { return (r & 7) << 4; }

// ---------------- k_pre (grid=8) ---------------- (unchanged)
__global__ __launch_bounds__(256) void k_pre(
    const float* __restrict__ Wc, const float* __restrict__ g1,
    const float* __restrict__ b1, const float* __restrict__ bc,
    const float* __restrict__ Wk, const float* __restrict__ Wq,
    const float* __restrict__ W2,
    float* __restrict__ u, float* __restrict__ v,
    _Float16* __restrict__ WcP, _Float16* __restrict__ WkP,
    float* __restrict__ WqT4, float* __restrict__ W2T4) {
    const int tid = threadIdx.x, bid = blockIdx.x;

    if (bid == 0) {  // u, v
        int j = tid;
        float su = 0.f, sv = 0.f;
        for (int c = 0; c < 128; c += 4) {
            f32x4 w = *(const f32x4*)(Wc + j * 128 + c);
            f32x4 g = *(const f32x4*)(g1 + c);
            f32x4 b = *(const f32x4*)(b1 + c);
#pragma unroll
            for (int e = 0; e < 4; ++e) { su += g[e] * w[e]; sv += b[e] * w[e]; }
        }
        u[j] = su;
        v[j] = sv + bc[j];
    }

    // WcP: 4096 f16x8 chunks, chunk ch = ((w*16 + ct*4 + ks)*64 + lane)
#pragma unroll
    for (int i = 0; i < 2; ++i) {
        int ch = bid * 512 + i * 256 + tid;
        int lane = ch & 63, ks = (ch >> 6) & 3, ct = (ch >> 8) & 3, w = ch >> 10;
        int j = w * 64 + ct * 16 + (lane & 15);
        int k0 = ks * 32 + (lane >> 4) * 8;
        f16x8 f;
#pragma unroll
        for (int h = 0; h < 2; ++h) {
            f32x4 wv = *(const f32x4*)(Wc + j * 128 + k0 + h * 4);
            f32x4 gv = *(const f32x4*)(g1 + k0 + h * 4);
#pragma unroll
            for (int e = 0; e < 4; ++e) f[h * 4 + e] = (_Float16)(wv[e] * gv[e]);
        }
        *(f16x8*)(WcP + ch * 8) = f;
    }

    // WkP: 2048 chunks, ch = ((w*8 + ks)*64 + lane)
    {
        int ch = bid * 256 + tid;
        int lane = ch & 63, ks = (ch >> 6) & 7, w = ch >> 9;
        int a = w * 16 + (lane & 15);
        int k0 = ks * 32 + (lane >> 4) * 8;
        f16x8 f;
#pragma unroll
        for (int h = 0; h < 2; ++h) {
            f32x4 wv = *(const f32x4*)(Wk + a * 256 + k0 + h * 4);
#pragma unroll
            for (int e = 0; e < 4; ++e) f[h * 4 + e] = (_Float16)wv[e];
        }
        *(f16x8*)(WkP + ch * 8) = f;
    }

    // WqT4: 4096 f32x4 chunks, idx = kb*64 + a; value = Wq[a][kb*4+e]
#pragma unroll
    for (int i = 0; i < 2; ++i) {
        int idx = bid * 512 + i * 256 + tid;
        int a = idx & 63, kb = idx >> 6;
        f32x4 wv = *(const f32x4*)(Wq + a * 256 + kb * 4);
        *(f32x4*)(WqT4 + idx * 4) = wv;
    }

    // W2T4: 1024 chunks, idx = kb*64 + a2; value = W2[a2][kb*4+e]
    if (tid < 128) {
        int idx = bid * 128 + tid;
        int a2 = idx & 63, kb = idx >> 6;
        f32x4 wv = *(const f32x4*)(W2 + a2 * 64 + kb * 4);
        *(f32x4*)(W2T4 + idx * 4) = wv;
    }
}

// ---------------- k_main ----------------
// LDS layout (bytes), 2px/block, phase-aliased (hazards barrier-separated):
#define XS_OFF 0        // [48][128] f16 swz (12288); PS2 scratch ph5a/5b;
                        // ph7+: KS f32[48][64] (12288)
#define OUTS_OFF 12288  // [48][256] f16 swz (24576); PS1 scratch ph2a/2b
#define AST_OFF 36864   // f32[48]
#define BST_OFF 37056   // f32[48]
#define U_OFF 37248     // f32[256]; OS f32[2][256] aliases U+V after ph4
#define V_OFF 38272     // f32[256]
#define G2_OFF 39296    // f32[256]; QB f32[2][64] @39296, Q2 @39808 after ph6
#define B2_OFF 40320    // f16[256]
#define SM1_SIZE 40832

#define KS_OFF 0
#define OS_OFF 37248
#define QB_OFF 39296
#define Q2_OFF 39808
#define ATTT_OFF 37248  // f32[48][16] = 3072 B over OS+QB+Q2 (after 9a barrier)

__global__ __launch_bounds__(256, 4) void k_main(
    const float* __restrict__ x,
    const float* __restrict__ uarr, const float* __restrict__ varr,
    const _Float16* __restrict__ WcP, const _Float16* __restrict__ WkP,
    const float* __restrict__ WqT4, const float* __restrict__ W2T4,
    const float* __restrict__ g2, const float* __restrict__ b2ln,
    const float* __restrict__ bq,
    const float* __restrict__ rm1, const float* __restrict__ rv1,
    const float* __restrict__ bg1, const float* __restrict__ bb1,
    const float* __restrict__ b2fc, const float* __restrict__ bk,
    _Float16* __restrict__ o_ws) {
    extern __shared__ char sm[];
    const int tid = threadIdx.x;
    const int lane = tid & 63;
    const int wave = tid >> 6;
    const int lrow = lane & 15;
    const int lkg = lane >> 4;  // 0..3
    // XCD-chunked swizzle: grid=8192, 8 XCDs, 1024 ids/chunk (bijective).
    const int wid = ((blockIdx.x & 7) << 10) | (blockIdx.x >> 3);
    const int p0 = wid * 2;
    const int bb = p0 >> 12;
    const int hh = (p0 >> 6) & 63;
    const int w0 = p0 & 63;  // even

    char* XS = sm + XS_OFF;
    char* OUTS = sm + OUTS_OFF;
    float* AST = (float*)(sm + AST_OFF);
    float* BST = (float*)(sm + BST_OFF);
    float* UU = (float*)(sm + U_OFF);
    float* VV = (float*)(sm + V_OFF);
    float* G2F = (float*)(sm + G2_OFF);
    _Float16* B2H = (_Float16*)(sm + B2_OFF);
    float* OS = (float*)(sm + OS_OFF);
    float* QB = (float*)(sm + QB_OFF);
    float* Q2 = (float*)(sm + Q2_OFF);
    float* ATTT = (float*)(sm + ATTT_OFF);
    float* KS = (float*)(sm + KS_OFF);
    float* PS1 = (float*)(sm + OUTS_OFF);  // [48][4][2] f32, dead-region scratch
    float* PS2 = (float*)(sm + XS_OFF);    // [48][4][2] f32, dead-region scratch

    // phase 0: LUTs
    UU[tid] = uarr[tid];
    VV[tid] = varr[tid];
    G2F[tid] = g2[tid];
    B2H[tid] = (_Float16)b2ln[tid];

    // phase 1: x tile -> XS (f32 -> f16, swizzled). rows r = pix*24+t, cols c.
#pragma unroll
    for (int i = 0; i < 12; ++i) {
        int idx = tid + i * 256;  // [0,3072)
        int c = idx / 24;
        int t = idx - c * 24;
        size_t go = (((size_t)((bb * 128 + c) * 24 + t)) << 12) + hh * 64 + w0;
        f32x2 xv = *(const f32x2*)(x + go);
#pragma unroll
        for (int p = 0; p < 2; ++p) {
            int r = p * 24 + t;
            *(_Float16*)(XS + r * 256 + ((c * 2) ^ swz(r))) = (_Float16)xv[p];
        }
    }
    __syncthreads();

    // phase 2a: LN1 stats partials, 4 threads/row -> PS1 (OUTS region, dead)
    if (tid < 192) {
        int r = tid >> 2, part = tid & 3;
        float s = 0.f, sq = 0.f;
#pragma unroll
        for (int i = 0; i < 4; ++i) {
            int kb = part * 4 + i;
            f16x8 v8 = *(const f16x8*)(XS + r * 256 + ((kb * 16) ^ swz(r)));
#pragma unroll
            for (int e = 0; e < 8; ++e) { float f = (float)v8[e]; s += f; sq += f * f; }
        }
        PS1[(r * 4 + part) * 2 + 0] = s;
        PS1[(r * 4 + part) * 2 + 1] = sq;
    }

    // phase 3: B-fragments from WcP (global loads, no LDS dependency)
    const int colbase = wave * 64;
    const _Float16* wcp = WcP + (size_t)wave * 1024 * 8;
    f16x8 bfr[4][4];
#pragma unroll
    for (int ct = 0; ct < 4; ++ct)
#pragma unroll
        for (int ks = 0; ks < 4; ++ks)
            bfr[ct][ks] = *(const f16x8*)(wcp + ((ct * 4 + ks) * 64 + lane) * 8);
    __syncthreads();

    // phase 2b: combine partials (fixed order, scalar reads) -> AST/BST
    if (tid < 48) {
        int r = tid;
        const float* p = PS1 + r * 8;
        float s = (p[0] + p[2]) + (p[4] + p[6]);
        float sq = (p[1] + p[3]) + (p[5] + p[7]);
        float m = s * (1.f / 128.f);
        float var = sq * (1.f / 128.f) - m * m;
        float inv = rsqrtf(var + EPSF);
        AST[r] = inv;
        BST[r] = m * inv;
    }
    __syncthreads();

    // phase 4: GEMM-A (out_pre = S*inv1 - (m1*inv1)*u + v), store f16 -> OUTS
#pragma unroll 1
    for (int rt = 0; rt < 3; ++rt) {
        int ra = rt * 16 + lrow;
        f16x8 af[4];
#pragma unroll
        for (int ks = 0; ks < 4; ++ks)
            af[ks] = *(const f16x8*)(XS + ra * 256 + ((ks * 64 + lkg * 16) ^ swz(ra)));
        f32x4 acc[4] = {};
#pragma unroll
        for (int ct = 0; ct < 4; ++ct)
#pragma unroll
            for (int ks = 0; ks < 4; ++ks)
                acc[ct] = __builtin_amdgcn_mfma_f32_16x16x32_f16(af[ks], bfr[ct][ks], acc[ct], 0, 0, 0);
        float a1r[4], b1r[4];
#pragma unroll
        for (int reg = 0; reg < 4; ++reg) {
            int rr = rt * 16 + lkg * 4 + reg;
            a1r[reg] = AST[rr];
            b1r[reg] = BST[rr];
        }
#pragma unroll
        for (int ct = 0; ct < 4; ++ct) {
            int j = colbase + ct * 16 + lrow;
            float uj = UU[j], vj = VV[j];
#pragma unroll
            for (int reg = 0; reg < 4; ++reg) {
                int rr = rt * 16 + lkg * 4 + reg;
                float val = acc[ct][reg] * a1r[reg] - b1r[reg] * uj + vj;
                *(_Float16*)(OUTS + rr * 512 + ((j * 2) ^ swz(rr))) = (_Float16)val;
            }
        }
    }
    __syncthreads();

    // phase 5a: LN2 stats partials, 4 threads/row -> PS2 (XS region, dead)
    if (tid < 192) {
        int r = tid >> 2, part = tid & 3;
        float s = 0.f, sq = 0.f;
#pragma unroll
        for (int i = 0; i < 8; ++i) {
            int kb = part * 8 + i;
            f16x8 v8 = *(const f16x8*)(OUTS + r * 512 + ((kb * 16) ^ swz(r)));
#pragma unroll
            for (int e = 0; e < 8; ++e) { float f = (float)v8[e]; s += f; sq += f * f; }
        }
        PS2[(r * 4 + part) * 2 + 0] = s;
        PS2[(r * 4 + part) * 2 + 1] = sq;
    }
    __syncthreads();

    // phase 5b: combine partials (fixed order, scalar reads) -> AST/BST
    if (tid < 48) {
        int r = tid;
        const float* p = PS2 + r * 8;
        float s = (p[0] + p[2]) + (p[4] + p[6]);
        float sq = (p[1] + p[3]) + (p[5] + p[7]);
        float m = s * (1.f / 256.f);
        float var = sq * (1.f / 256.f) - m * m;
        float inv = rsqrtf(var + EPSF);
        AST[r] = inv;
        BST[r] = m * inv;
    }
    __syncthreads();

    // phase 6: LN2 normalize in place (+g2,+b2) — round-7 form (2 thr/row)
    if (tid < 96) {
        int r = tid >> 1;
        int half = tid & 1;
        float a2r = AST[r], b2r = BST[r];
#pragma unroll
        for (int q = 0; q < 16; ++q) {
            int kb = half * 16 + q;
            char* p = OUTS + r * 512 + ((kb * 16) ^ swz(r));
            f16x8 v8 = *(const f16x8*)p;
#pragma unroll
            for (int e = 0; e < 8; ++e) {
                int j = kb * 8 + e;
                float f = (float)v8[e];
                f = f * a2r - b2r;
                f = f * G2F[j] + (float)B2H[j];
                v8[e] = (_Float16)f;
            }
            *(f16x8*)p = v8;
        }
    }
    __syncthreads();

    // phase 7: k-projection GEMM -> KS f32 [48][64] (over dead XS/PS2 region)
    {
        int aa = wave * 16 + lrow;
        const _Float16* wkp = WkP + (size_t)wave * 512 * 8;
        f16x8 kbf[8];
#pragma unroll
        for (int ks = 0; ks < 8; ++ks)
            kbf[ks] = *(const f16x8*)(wkp + (ks * 64 + lane) * 8);
        float bkf = bk[aa];
#pragma unroll 1
        for (int rt = 0; rt < 3; ++rt) {
            int ra = rt * 16 + lrow;
            f32x4 acc = {};
#pragma unroll
            for (int ks = 0; ks < 8; ++ks) {
                f16x8 af = *(const f16x8*)(OUTS + ra * 512 + ((ks * 64 + lkg * 16) ^ swz(ra)));
                acc = __builtin_amdgcn_mfma_f32_16x16x32_f16(af, kbf[ks], acc, 0, 0, 0);
            }
#pragma unroll
            for (int reg = 0; reg < 4; ++reg) {
                int rr = rt * 16 + lkg * 4 + reg;
                KS[rr * 64 + aa] = acc[reg] + bkf;
            }
        }
    }
    __syncthreads();

    // phase 8a: outsum (mean over T) -> OS — round-7 form (1 thr per 8 cols)
    if (tid < 64) {
        int pix = tid >> 5, j8 = tid & 31;
        float s[8] = {};
#pragma unroll
        for (int t = 0; t < 24; ++t) {
            int r = pix * 24 + t;
            f16x8 v8 = *(const f16x8*)(OUTS + r * 512 + ((j8 * 16) ^ swz(r)));
#pragma unroll
            for (int e = 0; e < 8; ++e) s[e] += (float)v8[e];
        }
#pragma unroll
        for (int e = 0; e < 8; ++e) OS[pix * 256 + j8 * 8 + e] = s[e] * (1.f / 24.f);
    }
    __syncthreads();

    // phase 8b: q_pre = os @ Wq.T + bq; then bn1 — ILP (4 accumulators),
    // SCALAR OS loads (HAZARD RULE: no f32x4 reads of OS/QB)
    if (tid < 128) {
        int pix = tid >> 6;
        int a = tid & 63;
        const float* osp = OS + pix * 256;
        float qa0 = 0.f, qa1 = 0.f, qa2 = 0.f, qa3 = 0.f;
#pragma unroll 2
        for (int kb = 0; kb < 64; kb += 4) {
            f32x4 w0 = *(const f32x4*)(WqT4 + ((kb + 0) * 64 + a) * 4);
            f32x4 w1 = *(const f32x4*)(WqT4 + ((kb + 1) * 64 + a) * 4);
            f32x4 w2 = *(const f32x4*)(WqT4 + ((kb + 2) * 64 + a) * 4);
            f32x4 w3 = *(const f32x4*)(WqT4 + ((kb + 3) * 64 + a) * 4);
            qa0 += osp[kb * 4 + 0] * w0[0] + osp[kb * 4 + 1] * w0[1] +
                   osp[kb * 4 + 2] * w0[2] + osp[kb * 4 + 3] * w0[3];
            qa1 += osp[kb * 4 + 4] * w1[0] + osp[kb * 4 + 5] * w1[1] +
                   osp[kb * 4 + 6] * w1[2] + osp[kb * 4 + 7] * w1[3];
            qa2 += osp[kb * 4 + 8] * w2[0] + osp[kb * 4 + 9] * w2[1] +
                   osp[kb * 4 + 10] * w2[2] + osp[kb * 4 + 11] * w2[3];
            qa3 += osp[kb * 4 + 12] * w3[0] + osp[kb * 4 + 13] * w3[1] +
                   osp[kb * 4 + 14] * w3[2] + osp[kb * 4 + 15] * w3[3];
        }
        float qp = ((qa0 + qa1) + (qa2 + qa3)) + bq[a];
        float sc = rsqrtf(rv1[a] + EPSF);
        QB[pix * 64 + a] = (qp - rm1[a]) * sc * bg1[a] + bb1[a];
    }
    __syncthreads();

    // phase 8c: q2 = qbn @ W2.T + b2 — ILP (2 accumulators), SCALAR QB loads
    if (tid < 128) {
        int pix = tid >> 6;
        int a2 = tid & 63;
        const float* qbp = QB + pix * 64;
        float s0 = 0.f, s1 = 0.f;
#pragma unroll
        for (int kb = 0; kb < 16; kb += 2) {
            f32x4 w0 = *(const f32x4*)(W2T4 + ((kb + 0) * 64 + a2) * 4);
            f32x4 w1 = *(const f32x4*)(W2T4 + ((kb + 1) * 64 + a2) * 4);
            s0 += qbp[kb * 4 + 0] * w0[0] + qbp[kb * 4 + 1] * w0[1] +
                  qbp[kb * 4 + 2] * w0[2] + qbp[kb * 4 + 3] * w0[3];
            s1 += qbp[kb * 4 + 4] * w1[0] + qbp[kb * 4 + 5] * w1[1] +
                  qbp[kb * 4 + 6] * w1[2] + qbp[kb * 4 + 7] * w1[3];
        }
        Q2[pix * 64 + a2] = (s0 + s1) + b2fc[a2];
    }
    __syncthreads();

    // phase 9a: scores + softmax (f32 KS) -> regs
    float att[24];
    if (tid < 32) {
        int pix = tid >> 4, hd = tid & 15;
        float q0 = Q2[pix * 64 + hd * 4 + 0];
        float q1 = Q2[pix * 64 + hd * 4 + 1];
        float q2v = Q2[pix * 64 + hd * 4 + 2];
        float q3 = Q2[pix * 64 + hd * 4 + 3];
        float mx = -1e30f;
#pragma unroll
        for (int t = 0; t < 24; ++t) {
            const float* kp = KS + (pix * 24 + t) * 64 + hd * 4;
            float s = 0.5f * (q0 * kp[0] + q1 * kp[1] + q2v * kp[2] + q3 * kp[3]);
            att[t] = s;
            mx = fmaxf(mx, s);
        }
        float sum = 0.f;
#pragma unroll
        for (int t = 0; t < 24; ++t) { float e = __expf(att[t] - mx); att[t] = e; sum += e; }
        float is = 1.f / sum;
#pragma unroll
        for (int t = 0; t < 24; ++t) att[t] *= is;
    }
    __syncthreads();  // Q2/KS reads done before ATTT overwrites

    // phase 9b: write attn weights TRANSPOSED -> ATTT [r][16h]
    if (tid < 32) {
        int pix = tid >> 4, hd = tid & 15;
#pragma unroll
        for (int t = 0; t < 24; ++t) ATTT[(pix * 24 + t) * 16 + hd] = att[t];
    }
    __syncthreads();

    // phase 10: o[n, h*256+d] = sum_t attn[h,t]*out[t,d]
    // 2 waves/pixel, 8 heads each; vector (broadcast) ATT loads.
    {
        int pix = wave >> 1;
        int hgrp = (wave & 1) * 8;
        f32x4 oa[8] = {};
#pragma unroll 1
        for (int t = 0; t < 24; ++t) {
            int r = pix * 24 + t;
            f16x4 v4 = *(const f16x4*)(OUTS + r * 512 + ((lane * 8) ^ swz(r)));
            f32x4 vf = {(float)v4[0], (float)v4[1], (float)v4[2], (float)v4[3]};
            f32x4 a0 = *(const f32x4*)(ATTT + r * 16 + hgrp);
            f32x4 a1 = *(const f32x4*)(ATTT + r * 16 + hgrp + 4);
#pragma unroll
            for (int h = 0; h < 4; ++h) oa[h] += a0[h] * vf;
#pragma unroll
            for (int h = 0; h < 4; ++h) oa[4 + h] += a1[h] * vf;
        }
        _Float16* op = o_ws + (size_t)(p0 + pix) * 4096 + (size_t)hgrp * 256 + lane * 4;
#pragma unroll
        for (int h = 0; h < 8; ++h) {
            f16x4 pk = {(_Float16)oa[h][0], (_Float16)oa[h][1],
                        (_Float16)oa[h][2], (_Float16)oa[h][3]};
            *(f16x4*)(op + h * 256) = pk;
        }
    }
}

// ---------------- k_mlp ---------------- (unchanged)
#define OT_OFF 0       // [64][256] f16 swz (32768); ZB aliases after GEMM
#define WT_OFF 32768   // [128][256] f16 swz (65536)
#define SC2_OFF 98304  // f32[128]
#define SH2_OFF 98816
#define G3_OFF 99328
#define B3_OFF 99840
#define A3_OFF 100352  // f32[64]
#define B3R_OFF 100608
#define SM3_SIZE 100864

__global__ __launch_bounds__(256) void k_mlp(
    const _Float16* __restrict__ o_ws,
    const float* __restrict__ Wm, const float* __restrict__ bm,
    const float* __restrict__ rm2, const float* __restrict__ rv2,
    const float* __restrict__ bg2, const float* __restrict__ bb2,
    const float* __restrict__ g3, const float* __restrict__ b3,
    float* __restrict__ out) {
    extern __shared__ char sm[];
    const int tid = threadIdx.x;
    const int lane = tid & 63;
    const int wave = tid >> 6;
    const int lrow = lane & 15;
    const int lkg = lane >> 4;
    const int n0 = blockIdx.x * 64;
    const int bb = blockIdx.x >> 6;
    const int hh = blockIdx.x & 63;

    char* OT = sm + OT_OFF;
    char* WT = sm + WT_OFF;
    char* ZB = sm + OT_OFF;  // f32 [64][128] swz, alias
    float* SC2 = (float*)(sm + SC2_OFF);
    float* SH2 = (float*)(sm + SH2_OFF);
    float* G3F = (float*)(sm + G3_OFF);
    float* B3F = (float*)(sm + B3_OFF);
    float* A3 = (float*)(sm + A3_OFF);
    float* B3R = (float*)(sm + B3R_OFF);

    if (tid < 128) {
        float sc = bg2[tid] * rsqrtf(rv2[tid] + EPSF);
        SC2[tid] = sc;
        SH2[tid] = bb2[tid] - rm2[tid] * sc + bm[tid] * sc;
        G3F[tid] = g3[tid];
        B3F[tid] = b3[tid];
    }

    const int colbase = wave * 32;
    f32x4 acc[4][2] = {};

    for (int kc = 0; kc < 16; ++kc) {
        __syncthreads();
#pragma unroll
        for (int i = 0; i < 8; ++i) {
            int fl = tid + i * 256;
            int r = fl >> 5, kk = fl & 31;
            f16x8 v = *(const f16x8*)(o_ws + (size_t)(n0 + r) * 4096 + kc * 256 + kk * 8);
            *(f16x8*)(OT + r * 512 + ((kk * 16) ^ swz(r))) = v;
        }
#pragma unroll
        for (int i = 0; i < 16; ++i) {
            int fl = tid + i * 256;
            int m = fl >> 5, kk = fl & 31;
            f16x8 f;
#pragma unroll
            for (int h = 0; h < 2; ++h) {
                f32x4 w = *(const f32x4*)(Wm + (size_t)m * 4096 + kc * 256 + kk * 8 + h * 4);
#pragma unroll
                for (int e = 0; e < 4; ++e) f[h * 4 + e] = (_Float16)w[e];
            }
            *(f16x8*)(WT + m * 512 + ((kk * 16) ^ swz(m))) = f;
        }
        __syncthreads();
        f16x8 bfr[2][8];
#pragma unroll
        for (int ct = 0; ct < 2; ++ct) {
            int m = colbase + ct * 16 + lrow;
#pragma unroll
            for (int ks = 0; ks < 8; ++ks)
                bfr[ct][ks] = *(const f16x8*)(WT + m * 512 + ((ks * 64 + lkg * 16) ^ swz(m)));
        }
#pragma unroll
        for (int rt = 0; rt < 4; ++rt) {
            int ra = rt * 16 + lrow;
#pragma unroll
            for (int ks = 0; ks < 8; ++ks) {
                f16x8 af = *(const f16x8*)(OT + ra * 512 + ((ks * 64 + lkg * 16) ^ swz(ra)));
#pragma unroll
                for (int ct = 0; ct < 2; ++ct)
                    acc[rt][ct] = __builtin_amdgcn_mfma_f32_16x16x32_f16(af, bfr[ct][ks], acc[rt][ct], 0, 0, 0);
            }
        }
    }
    __syncthreads();
#pragma unroll
    for (int rt = 0; rt < 4; ++rt) {
#pragma unroll
        for (int ct = 0; ct < 2; ++ct) {
            int m = colbase + ct * 16 + lrow;
            float sc = SC2[m], sh = SH2[m];
#pragma unroll
            for (int reg = 0; reg < 4; ++reg) {
                int rr = rt * 16 + lkg * 4 + reg;
                float z = acc[rt][ct][reg] * sc + sh;
                z = fmaxf(z, 0.f);
                *(float*)(ZB + rr * 512 + ((m * 4) ^ swz(rr))) = z;
            }
        }
    }
    __syncthreads();
    if (tid < 64) {
        int r = tid;
        float s = 0.f, sq = 0.f;
#pragma unroll
        for (int mb = 0; mb < 32; ++mb) {
            f32x4 v = *(const f32x4*)(ZB + r * 512 + ((mb * 16) ^ swz(r)));
#pragma unroll
            for (int e = 0; e < 4; ++e) { s += v[e]; sq += v[e] * v[e]; }
        }
        float m = s * (1.f / 128.f);
        float var = sq * (1.f / 128.f) - m * m;
        float inv = rsqrtf(var + EPSF);
        A3[r] = inv;
        B3R[r] = m * inv;
    }
    __syncthreads();
    {
        int m = tid >> 1;
        int half = tid & 1;
        float g = G3F[m], b = B3F[m];
        float vals[32];
#pragma unroll
        for (int i = 0; i < 32; ++i) {
            int w = half * 32 + i;
            float z = *(const float*)(ZB + w * 512 + ((m * 4) ^ swz(w)));
            vals[i] = (z * A3[w] - B3R[w]) * g + b;
        }
        float* po = out + ((size_t)(bb * 128 + m) * 64 + hh) * 64 + half * 32;
#pragma unroll
        for (int j = 0; j < 8; ++j) {
            f32x4 pk = {vals[j * 4], vals[j * 4 + 1], vals[j * 4 + 2], vals[j * 4 + 3]};
            *(f32x4*)(po + j * 4) = pk;
        }
    }
}

extern "C" void kernel_launch(void* const* d_in, const int* in_sizes, int n_in,
                              void* d_out, int out_size, void* d_ws, size_t ws_size,
                              hipStream_t stream) {
    const float* x = (const float*)d_in[0];
    const float* g1 = (const float*)d_in[1];
    const float* b1 = (const float*)d_in[2];
    const float* Wc = (const float*)d_in[3];
    const float* bc = (const float*)d_in[4];
    const float* g2 = (const float*)d_in[5];
    const float* b2l = (const float*)d_in[6];
    const float* Wq = (const float*)d_in[7];
    const float* bq = (const float*)d_in[8];
    const float* rm1 = (const float*)d_in[9];
    const float* rv1 = (const float*)d_in[10];
    const float* bg1 = (const float*)d_in[11];
    const float* bb1 = (const float*)d_in[12];
    const float* W2 = (const float*)d_in[13];
    const float* b2f = (const float*)d_in[14];
    const float* Wk = (const float*)d_in[15];
    const float* bk = (const float*)d_in[16];
    const float* Wm = (const float*)d_in[17];
    const float* bm = (const float*)d_in[18];
    const float* rm2 = (const float*)d_in[19];
    const float* rv2 = (const float*)d_in[20];
    const float* bg2 = (const float*)d_in[21];
    const float* bb2 = (const float*)d_in[22];
    const float* g3 = (const float*)d_in[23];
    const float* b3 = (const float*)d_in[24];

    // ws layout (byte offsets):
    //   0       u      f32[256]
    //   1024    v      f32[256]
    //   2048    WcP    f16[32768]   (64 KB)
    //   67584   WkP    f16[16384]   (32 KB)
    //   100352  WqT4   f32[16384]   (64 KB)
    //   165888  W2T4   f32[4096]    (16 KB)
    //   182272  o_ws   f16[16384*4096] (128 MiB)
    float* u = (float*)d_ws;
    float* v = u + 256;
    _Float16* WcP = (_Float16*)((char*)d_ws + 2048);
    _Float16* WkP = (_Float16*)((char*)d_ws + 67584);
    float* WqT4 = (float*)((char*)d_ws + 100352);
    float* W2T4 = (float*)((char*)d_ws + 165888);
    _Float16* o_ws = (_Float16*)((char*)d_ws + 182272);

    (void)hipFuncSetAttribute((const void*)k_mlp,
                              hipFuncAttributeMaxDynamicSharedMemorySize, SM3_SIZE);

    k_pre<<<8, 256, 0, stream>>>(Wc, g1, b1, bc, Wk, Wq, W2, u, v, WcP, WkP, WqT4, W2T4);
    k_main<<<8192, 256, SM1_SIZE, stream>>>(x, u, v, WcP, WkP, WqT4, W2T4,
                                            g2, b2l, bq, rm1, rv1, bg1, bb1, b2f, bk, o_ws);
    k_mlp<<<256, 256, SM3_SIZE, stream>>>(o_ws, Wm, bm, rm2, rv2, bg2, bb2, g3, b3,
                                          (float*)d_out);
}